// Round 11
// baseline (152.376 us; speedup 1.0000x reference)
//
#include <hip/hip_runtime.h>

// CapsuleLayer: bf16 MFMA (16x16x32), round-4 block structure tuned for the
// 128-register occupancy cliff: acc[9] (36 AGPR) via nf-split, A-frags
// streamed (transient), total regs < 128 -> 4 waves/SIMD.
// Sizes: B=8, C=128, H=W=32, K=3, pad=1 -> oh=ow=32, NC=512, 3 routing iters.
//
// d_ws: wT bf16 [9][512][128] (k-contig) ; inT bf16 [8][34][34][128] padded+swizzled.
// Swizzle: within each 256B channel-block of padded cell w, byte ^= (w&15)<<4.

typedef __bf16 bf16x8 __attribute__((ext_vector_type(8)));
typedef float  f32x4  __attribute__((ext_vector_type(4)));

#define NC    512
#define CIN   128
#define HW    32
#define INT_H 34
#define INT_W 34
#define ROWB  (INT_W * 256)          // 8704 B per padded row
#define WT_ELEMS (9 * NC * CIN)

// ---- fused prepass: blocks [0,288) -> wT ; [288, 866) -> inT (incl. borders) ----
__global__ __launch_bounds__(256)
void prepass(const float* __restrict__ in, const float* __restrict__ wgt,
             __bf16* __restrict__ wT, __bf16* __restrict__ inT) {
    const int t = threadIdx.x;
    if (blockIdx.x < 288) {
        int g   = blockIdx.x * 256 + t;     // 73728
        int n   = g & 511;
        int cb  = (g >> 9) & 15;
        int tap = g >> 13;
        bf16x8 v;
        #pragma unroll
        for (int k = 0; k < 8; k++)
            v[k] = (__bf16)wgt[(tap * CIN + cb * 8 + k) * NC + n];
        *(bf16x8*)(wT + ((size_t)tap * NC + n) * CIN + cb * 8) = v;
    } else {
        int g    = (blockIdx.x - 288) * 256 + t;   // 147968 = 8*34*34*16
        int cb   = g & 15;
        int cell = g >> 4;
        int w    = cell % INT_W;
        int rest = cell / INT_W;
        int h    = rest % INT_H;
        int b    = rest / INT_H;
        bf16x8 v;
        #pragma unroll
        for (int k = 0; k < 8; k++) v[k] = (__bf16)0.0f;
        if (h >= 1 && h <= 32 && w >= 1 && w <= 32) {
            #pragma unroll
            for (int k = 0; k < 8; k++)
                v[k] = (__bf16)in[((b * CIN + cb * 8 + k) * HW + (h - 1)) * HW + (w - 1)];
        }
        int within = (cb * 16) ^ ((w & 15) << 4);
        *(bf16x8*)((char*)inT + (size_t)(b * INT_H + h) * ROWB + w * 256 + within) = v;
    }
}

// ---- main: block = 64 channels (4 waves x 16ch) x 32 positions (one h-row) ----
__global__ __launch_bounds__(256, 4)
void caps_main(const __bf16* __restrict__ wT, const __bf16* __restrict__ inT,
               const float* __restrict__ bias, float* __restrict__ out) {
    __shared__ __attribute__((aligned(16))) unsigned char brow[3 * ROWB];  // 26112 B

    const int x    = blockIdx.x;          // 2048 blocks
    const int nblk = x & 7;
    const int bh   = x >> 3;
    const int h    = bh & 31;
    const int b    = bh >> 5;
    const int t    = threadIdx.x;
    const int lane = t & 63;
    const int wm   = t >> 6;
    const int l15  = lane & 15;
    const int l4   = lane >> 4;
    const int nb   = nblk * 64 + wm * 16;

    // ---- stage padded rows [h, h+2] (26112 B contiguous) via global_load_lds ----
    {
        const char* src = (const char*)inT + (size_t)(b * INT_H + h) * ROWB;
        #pragma unroll
        for (int i = 0; i < 7; i++) {
            int c = wm + i * 4;                 // 1KB chunk id
            if (c < 25) {
                __builtin_amdgcn_global_load_lds((const unsigned*)(src + c * 1024 + lane * 16),
                                                 (unsigned*)(brow + c * 1024), 16, 0, 0);
            } else if (c == 25 && lane < 32) {  // tail 512 B
                __builtin_amdgcn_global_load_lds((const unsigned*)(src + c * 1024 + lane * 16),
                                                 (unsigned*)(brow + c * 1024), 16, 0, 0);
            }
        }
    }
    __syncthreads();

    const __bf16* aptr = wT + (size_t)(nb + l15) * CIN + l4 * 8;

    // ---- two independent 16-position half-rows, processed sequentially ----
    #pragma unroll 1
    for (int nf = 0; nf < 2; ++nf) {
        f32x4 acc[9];
        #pragma unroll
        for (int tap = 0; tap < 9; tap++)
            acc[tap] = *(const f32x4*)(bias + tap * NC + nb + l4 * 4);

        #pragma unroll
        for (int i = 0; i < 3; i++) {
            #pragma unroll
            for (int j = 0; j < 3; j++) {
                const int tap = i * 3 + j;
                #pragma unroll
                for (int kk = 0; kk < 4; kk++) {
                    bf16x8 a = *(const bf16x8*)(aptr + (size_t)(tap * NC) * CIN + kk * 32);
                    int pos = j + nf * 16 + l15;
                    int off = i * ROWB + pos * 256 + ((kk * 64 + l4 * 16) ^ ((pos & 15) << 4));
                    bf16x8 bv = *(const bf16x8*)(brow + off);
                    acc[tap] = __builtin_amdgcn_mfma_f32_16x16x32_bf16(a, bv, acc[tap], 0, 0, 0);
                }
            }
        }

        // ---- routing (16 positions) ----
        f32x4 o = acc[0];
        #pragma unroll
        for (int tap = 1; tap < 9; tap++) o += acc[tap];
        o = o * (1.0f / 9.0f);

        #pragma unroll
        for (int it = 0; it < 3; it++) {
            float cw[9];
            float S = 0.f;
            #pragma unroll
            for (int tap = 0; tap < 9; tap++) {
                f32x4 d = o - acc[tap];
                float d2 = d[0] * d[0] + d[1] * d[1] + d[2] * d[2] + d[3] * d[3];
                d2 += __shfl_xor(d2, 16);
                d2 += __shfl_xor(d2, 32);
                float rr = __builtin_amdgcn_rsqf(d2 + 1e-4f);
                cw[tap] = rr;
                S += rr;
            }
            float inv = __builtin_amdgcn_rcpf(S);
            f32x4 on = acc[0] * cw[0];
            #pragma unroll
            for (int tap = 1; tap < 9; tap++) on += acc[tap] * cw[tap];
            o = on * inv;
        }

        // ---- store: out[b][n][h][w], n = nb + l4*4 + reg, w = nf*16 + l15 ----
        size_t obase = ((size_t)(b * NC + nb + l4 * 4) * HW + h) * HW + nf * 16 + l15;
        #pragma unroll
        for (int reg = 0; reg < 4; reg++)
            out[obase + (size_t)reg * HW * HW] = o[reg];
    }
}

extern "C" void kernel_launch(void* const* d_in, const int* in_sizes, int n_in,
                              void* d_out, int out_size, void* d_ws, size_t ws_size,
                              hipStream_t stream) {
    const float* in   = (const float*)d_in[0];
    const float* wgt  = (const float*)d_in[1];
    const float* bias = (const float*)d_in[2];
    float* out = (float*)d_out;

    __bf16* wT  = (__bf16*)d_ws;
    __bf16* inT = wT + WT_ELEMS;

    prepass<<<866, 256, 0, stream>>>(in, wgt, wT, inT);

    dim3 grid(256 * 8);   // (b,h) x 8 nblk = 2048 blocks
    caps_main<<<grid, 256, 0, stream>>>(wT, inT, bias, out);
}

// Round 12
// 151.457 us; speedup vs baseline: 1.0061x; 1.0061x over previous
//
#include <hip/hip_runtime.h>

// CapsuleLayer: bf16 MFMA (16x16x32), nf-split (acc[9]=36 regs), A streamed,
// 4 waves/SIMD. sched_group_barrier pins per-tap {5 VMEM_READ, 4 DS_READ,
// 4 MFMA} clusters so the scheduler cannot hoist all 36 A-loads (the r11
// spill cause). Sizes: B=8, C=128, H=W=32, K=3, pad=1 -> oh=ow=32, NC=512.
//
// d_ws: wT bf16 [9][512][128] (k-contig) ; inT bf16 [8][34][34][128] padded+swizzled.
// Swizzle: within each 256B channel-block of padded cell w, byte ^= (w&15)<<4.

typedef __bf16 bf16x8 __attribute__((ext_vector_type(8)));
typedef float  f32x4  __attribute__((ext_vector_type(4)));

#define NC    512
#define CIN   128
#define HW    32
#define INT_H 34
#define INT_W 34
#define ROWB  (INT_W * 256)          // 8704 B per padded row
#define WT_ELEMS (9 * NC * CIN)
#define SGB __builtin_amdgcn_sched_group_barrier

// ---- fused prepass: blocks [0,288) -> wT ; [288, 866) -> inT (incl. borders) ----
__global__ __launch_bounds__(256)
void prepass(const float* __restrict__ in, const float* __restrict__ wgt,
             __bf16* __restrict__ wT, __bf16* __restrict__ inT) {
    const int t = threadIdx.x;
    if (blockIdx.x < 288) {
        int g   = blockIdx.x * 256 + t;     // 73728
        int n   = g & 511;
        int cb  = (g >> 9) & 15;
        int tap = g >> 13;
        bf16x8 v;
        #pragma unroll
        for (int k = 0; k < 8; k++)
            v[k] = (__bf16)wgt[(tap * CIN + cb * 8 + k) * NC + n];
        *(bf16x8*)(wT + ((size_t)tap * NC + n) * CIN + cb * 8) = v;
    } else {
        int g    = (blockIdx.x - 288) * 256 + t;   // 147968 = 8*34*34*16
        int cb   = g & 15;
        int cell = g >> 4;
        int w    = cell % INT_W;
        int rest = cell / INT_W;
        int h    = rest % INT_H;
        int b    = rest / INT_H;
        bf16x8 v;
        #pragma unroll
        for (int k = 0; k < 8; k++) v[k] = (__bf16)0.0f;
        if (h >= 1 && h <= 32 && w >= 1 && w <= 32) {
            #pragma unroll
            for (int k = 0; k < 8; k++)
                v[k] = (__bf16)in[((b * CIN + cb * 8 + k) * HW + (h - 1)) * HW + (w - 1)];
        }
        int within = (cb * 16) ^ ((w & 15) << 4);
        *(bf16x8*)((char*)inT + (size_t)(b * INT_H + h) * ROWB + w * 256 + within) = v;
    }
}

// ---- main: block = 64 channels (4 waves x 16ch) x 32 positions (one h-row) ----
__global__ __launch_bounds__(256, 4)
void caps_main(const __bf16* __restrict__ wT, const __bf16* __restrict__ inT,
               const float* __restrict__ bias, float* __restrict__ out) {
    __shared__ __attribute__((aligned(16))) unsigned char brow[3 * ROWB];  // 26112 B

    const int x    = blockIdx.x;          // 2048 blocks
    const int nblk = x & 7;
    const int bh   = x >> 3;
    const int h    = bh & 31;
    const int b    = bh >> 5;
    const int t    = threadIdx.x;
    const int lane = t & 63;
    const int wm   = t >> 6;
    const int l15  = lane & 15;
    const int l4   = lane >> 4;
    const int nb   = nblk * 64 + wm * 16;

    // ---- stage padded rows [h, h+2] (26112 B contiguous) via global_load_lds ----
    {
        const char* src = (const char*)inT + (size_t)(b * INT_H + h) * ROWB;
        #pragma unroll
        for (int i = 0; i < 7; i++) {
            int c = wm + i * 4;                 // 1KB chunk id
            if (c < 25) {
                __builtin_amdgcn_global_load_lds((const unsigned*)(src + c * 1024 + lane * 16),
                                                 (unsigned*)(brow + c * 1024), 16, 0, 0);
            } else if (c == 25 && lane < 32) {  // tail 512 B
                __builtin_amdgcn_global_load_lds((const unsigned*)(src + c * 1024 + lane * 16),
                                                 (unsigned*)(brow + c * 1024), 16, 0, 0);
            }
        }
    }
    __syncthreads();

    const __bf16* aptr = wT + (size_t)(nb + l15) * CIN + l4 * 8;

    // ---- two independent 16-position half-rows, processed sequentially ----
    #pragma unroll 1
    for (int nf = 0; nf < 2; ++nf) {
        f32x4 acc[9];

        #pragma unroll
        for (int tap = 0; tap < 9; tap++) {
            const int i = tap / 3, j = tap % 3;
            // acc init = bias (1 VMEM_READ, part of this tap's group)
            f32x4 a = *(const f32x4*)(bias + tap * NC + nb + l4 * 4);
            const __bf16* ap = aptr + (size_t)(tap * NC) * CIN;
            const int pos = j + nf * 16 + l15;
            const unsigned char* bp = brow + i * ROWB + pos * 256;
            const int sw = (pos & 15) << 4;
            #pragma unroll
            for (int kk = 0; kk < 4; kk++) {
                bf16x8 av = *(const bf16x8*)(ap + kk * 32);
                bf16x8 bv = *(const bf16x8*)(bp + ((kk * 64 + l4 * 16) ^ sw));
                a = __builtin_amdgcn_mfma_f32_16x16x32_bf16(av, bv, a, 0, 0, 0);
            }
            acc[tap] = a;
            // pin this tap's cluster: 4 A-frags + 1 bias, then 4 ds_reads, 4 MFMA.
            SGB(0x020, 5, 0);   // VMEM_READ
            SGB(0x100, 4, 0);   // DS_READ
            SGB(0x008, 4, 0);   // MFMA
        }

        // ---- routing (16 positions) ----
        f32x4 o = acc[0];
        #pragma unroll
        for (int tap = 1; tap < 9; tap++) o += acc[tap];
        o = o * (1.0f / 9.0f);

        #pragma unroll
        for (int it = 0; it < 3; it++) {
            float cw[9];
            float S = 0.f;
            #pragma unroll
            for (int tap = 0; tap < 9; tap++) {
                f32x4 d = o - acc[tap];
                float d2 = d[0] * d[0] + d[1] * d[1] + d[2] * d[2] + d[3] * d[3];
                d2 += __shfl_xor(d2, 16);
                d2 += __shfl_xor(d2, 32);
                float rr = __builtin_amdgcn_rsqf(d2 + 1e-4f);
                cw[tap] = rr;
                S += rr;
            }
            float inv = __builtin_amdgcn_rcpf(S);
            f32x4 on = acc[0] * cw[0];
            #pragma unroll
            for (int tap = 1; tap < 9; tap++) on += acc[tap] * cw[tap];
            o = on * inv;
        }

        // ---- store: out[b][n][h][w], n = nb + l4*4 + reg, w = nf*16 + l15 ----
        size_t obase = ((size_t)(b * NC + nb + l4 * 4) * HW + h) * HW + nf * 16 + l15;
        #pragma unroll
        for (int reg = 0; reg < 4; reg++)
            out[obase + (size_t)reg * HW * HW] = o[reg];
    }
}

extern "C" void kernel_launch(void* const* d_in, const int* in_sizes, int n_in,
                              void* d_out, int out_size, void* d_ws, size_t ws_size,
                              hipStream_t stream) {
    const float* in   = (const float*)d_in[0];
    const float* wgt  = (const float*)d_in[1];
    const float* bias = (const float*)d_in[2];
    float* out = (float*)d_out;

    __bf16* wT  = (__bf16*)d_ws;
    __bf16* inT = wT + WT_ELEMS;

    prepass<<<866, 256, 0, stream>>>(in, wgt, wT, inT);

    dim3 grid(256 * 8);   // (b,h) x 8 nblk = 2048 blocks
    caps_main<<<grid, 256, 0, stream>>>(wT, inT, bias, out);
}